// Round 4
// baseline (133.946 us; speedup 1.0000x reference)
//
#include <hip/hip_runtime.h>
#include <math.h>

// SO3 convolution lmax=2 — 3 dispatches:
//   0) memsetAsync cnt[A] = 0
//   1) prep_kernel: one 64-thread block per edge.
//      - M_e[s1][s3] = sum_k cg_val[k]*Y_e[i2[k]] at (i1[k],i3[k]) via LDS
//        atomics, stored TRANSPOSED to ws (81 of 96 padded dwords/edge).
//      - Wij[e,3,128] = (radial[e] @ W_filter + b) * cutoff  (radial matvec
//        done exactly once per edge, massively parallel).
//      - per-atom edge list build: pos = atomicAdd(cnt[idx_i[e]]); elist[..]=e
//        (replaces hist+scan+scatter; MAXDEG=128 >> max Poisson(10) degree).
//   2) atom_kernel: one wave per atom. Per edge: uniform s_load of M (81
//      dwords), 12 float2 vector loads, ~99 v_pk_fma_f32. Output written once
//      (no atomics, no out memset, no slots, no reduce kernel).

#define S9      9
#define NF      128
#define NRAD    20
#define MAXDEG  128
#define MSTRIDE 96      // padded dwords per edge for M (81 used, 384B-aligned)

__device__ inline float2 f2fma(float a, float2 b, float2 c) {
    return make_float2(fmaf(a, b.x, c.x), fmaf(a, b.y, c.y));
}

// ---------------- kernel 1: per-edge prep ----------------
__global__ __launch_bounds__(64) void prep_kernel(
    const float* __restrict__ radial,   // [E, 20]
    const float* __restrict__ dir,      // [E, 3]
    const float* __restrict__ cutoff,   // [E]
    const float* __restrict__ Wf,       // [20, 384]
    const float* __restrict__ bf,       // [384]
    const float* __restrict__ cg_vals,  // [ncg]
    const int* __restrict__ idx_i,      // [E]
    const int* __restrict__ cg_i1,
    const int* __restrict__ cg_i2,
    const int* __restrict__ cg_i3,
    int ncg,
    int* __restrict__ cnt,              // [A]
    int* __restrict__ elist,            // [A, MAXDEG]
    float* __restrict__ Mall,           // [E, MSTRIDE]  (M transposed [s1][s3])
    float* __restrict__ Wij)            // [E, 3, 128]
{
    const int e = blockIdx.x;
    const int t = threadIdx.x;

    __shared__ float Msh[81];
    __shared__ float Ysh[9];

    if (t < 81) Msh[t] = 0.0f;
    if (t + 64 < 81) Msh[t + 64] = 0.0f;

    if (t == 0) {
        float dx = dir[3 * e], dy = dir[3 * e + 1], dz = dir[3 * e + 2];
        const float inv = rsqrtf(dx * dx + dy * dy + dz * dz);
        dx *= inv; dy *= inv; dz *= inv;
        const float s3c  = 1.7320508075688772f;   // sqrt(3)
        const float s5c  = 2.2360679774997896f;   // sqrt(5)
        const float s15c = 3.8729833462074170f;   // sqrt(15)
        Ysh[0] = 1.0f;
        Ysh[1] = s3c * dy;
        Ysh[2] = s3c * dz;
        Ysh[3] = s3c * dx;
        Ysh[4] = s15c * dx * dy;
        Ysh[5] = s15c * dy * dz;
        Ysh[6] = 0.5f * s5c * (3.0f * dz * dz - 1.0f);
        Ysh[7] = s15c * dx * dz;
        Ysh[8] = 0.5f * s15c * (dx * dx - dy * dy);
        // per-atom edge-list slot
        const int i = idx_i[e];
        const int pos = atomicAdd(&cnt[i], 1);
        if (pos < MAXDEG) elist[i * MAXDEG + pos] = e;
    }
    __syncthreads();

    // sparse CG -> M (transposed: slot = s1*9 + s3)
    for (int k = t; k < ncg; k += 64)
        atomicAdd(&Msh[cg_i1[k] * S9 + cg_i3[k]], cg_vals[k] * Ysh[cg_i2[k]]);

    // radial filter (independent of Msh; overlaps the LDS atomics)
    float rad[NRAD];
    #pragma unroll
    for (int r = 0; r < NRAD; ++r) rad[r] = radial[e * NRAD + r];
    const float cut = cutoff[e];

    float2 w0 = ((const float2*)(bf + 0 * NF))[t];
    float2 w1 = ((const float2*)(bf + 1 * NF))[t];
    float2 w2 = ((const float2*)(bf + 2 * NF))[t];
    #pragma unroll
    for (int r = 0; r < NRAD; ++r) {
        const float2* row = (const float2*)(Wf + r * (3 * NF));
        w0 = f2fma(rad[r], row[t],       w0);
        w1 = f2fma(rad[r], row[t + 64],  w1);
        w2 = f2fma(rad[r], row[t + 128], w2);
    }
    w0.x *= cut; w0.y *= cut;
    w1.x *= cut; w1.y *= cut;
    w2.x *= cut; w2.y *= cut;

    float2* wp = (float2*)(Wij + (size_t)e * (3 * NF));
    wp[t]       = w0;
    wp[t + 64]  = w1;
    wp[t + 128] = w2;

    __syncthreads();
    float* mp = Mall + (size_t)e * MSTRIDE;
    if (t < 81) mp[t] = Msh[t];
    if (t + 64 < 81) mp[t + 64] = Msh[t + 64];
}

// ---------------- kernel 2: one wave per atom ----------------
__global__ __launch_bounds__(64) void atom_kernel(
    const float* __restrict__ x,        // [A, 9, 128]
    const float* __restrict__ Mall,     // [E, MSTRIDE]
    const float* __restrict__ Wij,      // [E, 3, 128]
    const int* __restrict__ cnt,        // [A]
    const int* __restrict__ elist,      // [A, MAXDEG]
    const int* __restrict__ idx_j,      // [E]
    float* __restrict__ out)            // [A, 9, 128]
{
    const int a = blockIdx.x;
    const int t = threadIdx.x;          // f-pair: f = 2t, 2t+1
    const int deg = min(cnt[a], MAXDEG);
    const int* el = elist + a * MAXDEG;

    float2 acc[S9];
    #pragma unroll
    for (int s = 0; s < S9; ++s) acc[s] = make_float2(0.f, 0.f);

    #pragma unroll 2
    for (int k = 0; k < deg; ++k) {
        const int e = __builtin_amdgcn_readfirstlane(el[k]);
        const int j = __builtin_amdgcn_readfirstlane(idx_j[e]);

        const float*  Me = Mall + (size_t)e * MSTRIDE;        // uniform -> SMEM
        const float2* xp = (const float2*)(x + (size_t)j * (S9 * NF)) + t;
        const float2* wp = (const float2*)(Wij + (size_t)e * (3 * NF)) + t;

        float2 xj[S9];
        #pragma unroll
        for (int s = 0; s < S9; ++s) xj[s] = xp[s * 64];
        const float2 wl0 = wp[0];
        const float2 wl1 = wp[64];
        const float2 wl2 = wp[128];

        // ts[s3] = sum_s1 M[s1][s3] * xj[s1]   (M stored [s1][s3])
        float2 ts[S9];
        #pragma unroll
        for (int s3 = 0; s3 < S9; ++s3)
            ts[s3] = make_float2(Me[s3] * xj[0].x, Me[s3] * xj[0].y);
        #pragma unroll
        for (int s1 = 1; s1 < S9; ++s1) {
            #pragma unroll
            for (int s3 = 0; s3 < S9; ++s3)
                ts[s3] = f2fma(Me[s1 * S9 + s3], xj[s1], ts[s3]);
        }
        #pragma unroll
        for (int s3 = 0; s3 < S9; ++s3) {
            const float2 w = (s3 == 0) ? wl0 : ((s3 < 4) ? wl1 : wl2);
            acc[s3].x = fmaf(w.x, ts[s3].x, acc[s3].x);
            acc[s3].y = fmaf(w.y, ts[s3].y, acc[s3].y);
        }
    }

    float2* op = (float2*)(out + (size_t)a * (S9 * NF)) + t;
    #pragma unroll
    for (int s = 0; s < S9; ++s) op[s * 64] = acc[s];
}

extern "C" void kernel_launch(void* const* d_in, const int* in_sizes, int n_in,
                              void* d_out, int out_size, void* d_ws, size_t ws_size,
                              hipStream_t stream) {
    const float* x       = (const float*)d_in[0];
    const float* radial  = (const float*)d_in[1];
    const float* dir     = (const float*)d_in[2];
    const float* cutoff  = (const float*)d_in[3];
    const float* Wf      = (const float*)d_in[4];
    const float* bf      = (const float*)d_in[5];
    const float* cg_vals = (const float*)d_in[6];
    const int*   idx_i   = (const int*)d_in[7];
    const int*   idx_j   = (const int*)d_in[8];
    const int*   cg_i1   = (const int*)d_in[9];
    const int*   cg_i2   = (const int*)d_in[10];
    const int*   cg_i3   = (const int*)d_in[11];
    // d_in[12] = w_idx: unused (w_idx[k] == l(cg_idx_out[k]), folded into kernel)

    const int E   = in_sizes[7];
    const int ncg = in_sizes[6];
    const int A   = in_sizes[0] / (S9 * NF);

    // ws layout: cnt[A] | elist[A*MAXDEG] | (align 512B) | Mall[E*96] | Wij[E*384]
    int* cnt   = (int*)d_ws;
    int* elist = cnt + A;
    size_t off = ((size_t)(A + A * MAXDEG) * sizeof(int) + 511) & ~(size_t)511;
    float* Mall = (float*)((char*)d_ws + off);
    float* Wij  = Mall + (size_t)E * MSTRIDE;

    hipMemsetAsync(cnt, 0, (size_t)A * sizeof(int), stream);

    prep_kernel<<<E, 64, 0, stream>>>(
        radial, dir, cutoff, Wf, bf, cg_vals, idx_i,
        cg_i1, cg_i2, cg_i3, ncg, cnt, elist, Mall, Wij);

    atom_kernel<<<A, 64, 0, stream>>>(
        x, Mall, Wij, cnt, elist, idx_j, (float*)d_out);
}

// Round 5
// 131.451 us; speedup vs baseline: 1.0190x; 1.0190x over previous
//
#include <hip/hip_runtime.h>
#include <math.h>

// SO3 convolution lmax=2 — 3 dispatches:
//   0) memsetAsync cnt[A] = 0
//   1) prep_kernel (E blocks x 64): per-edge M (transposed [s1][s3]) -> Mall,
//      radial filter Wij[e,3,128], and per-atom edge list via cursor atomic.
//   2) atom_kernel (A blocks x 256 = 4 waves): wave w handles edges w, w+4,...
//      with e/j prefetched one iteration ahead (scalar chain halved); per edge
//      uniform s_loads of M, float2 loads of Wij/xj, ~99 pk-FMAs; 4-wave LDS
//      reduction; single coalesced store. No float atomics anywhere.

#define S9      9
#define NF      128
#define NRAD    20
#define MAXDEG  64
#define MSTRIDE 96      // padded dwords per edge for M (81 used)

__device__ inline float2 f2fma(float a, float2 b, float2 c) {
    return make_float2(fmaf(a, b.x, c.x), fmaf(a, b.y, c.y));
}

// ---------------- kernel 1: per-edge prep ----------------
__global__ __launch_bounds__(64) void prep_kernel(
    const float* __restrict__ radial,   // [E, 20]
    const float* __restrict__ dir,      // [E, 3]
    const float* __restrict__ cutoff,   // [E]
    const float* __restrict__ Wf,       // [20, 384]
    const float* __restrict__ bf,       // [384]
    const float* __restrict__ cg_vals,  // [ncg]
    const int* __restrict__ idx_i,      // [E]
    const int* __restrict__ cg_i1,
    const int* __restrict__ cg_i2,
    const int* __restrict__ cg_i3,
    int ncg,
    int* __restrict__ cnt,              // [A]
    int* __restrict__ elist,            // [A, MAXDEG]
    float* __restrict__ Mall,           // [E, MSTRIDE]  (M transposed [s1][s3])
    float* __restrict__ Wij)            // [E, 3, 128]
{
    const int e = blockIdx.x;
    const int t = threadIdx.x;

    __shared__ float Msh[81];
    __shared__ float Ysh[9];

    if (t < 81) Msh[t] = 0.0f;
    if (t + 64 < 81) Msh[t + 64] = 0.0f;

    if (t == 0) {
        float dx = dir[3 * e], dy = dir[3 * e + 1], dz = dir[3 * e + 2];
        const float inv = rsqrtf(dx * dx + dy * dy + dz * dz);
        dx *= inv; dy *= inv; dz *= inv;
        const float s3c  = 1.7320508075688772f;   // sqrt(3)
        const float s5c  = 2.2360679774997896f;   // sqrt(5)
        const float s15c = 3.8729833462074170f;   // sqrt(15)
        Ysh[0] = 1.0f;
        Ysh[1] = s3c * dy;
        Ysh[2] = s3c * dz;
        Ysh[3] = s3c * dx;
        Ysh[4] = s15c * dx * dy;
        Ysh[5] = s15c * dy * dz;
        Ysh[6] = 0.5f * s5c * (3.0f * dz * dz - 1.0f);
        Ysh[7] = s15c * dx * dz;
        Ysh[8] = 0.5f * s15c * (dx * dx - dy * dy);
        const int i = idx_i[e];
        const int pos = atomicAdd(&cnt[i], 1);
        if (pos < MAXDEG) elist[i * MAXDEG + pos] = e;
    }
    __syncthreads();

    // sparse CG -> M (transposed: slot = s1*9 + s3)
    for (int k = t; k < ncg; k += 64)
        atomicAdd(&Msh[cg_i1[k] * S9 + cg_i3[k]], cg_vals[k] * Ysh[cg_i2[k]]);

    // radial filter (overlaps the LDS atomics)
    float rad[NRAD];
    #pragma unroll
    for (int r = 0; r < NRAD; ++r) rad[r] = radial[e * NRAD + r];
    const float cut = cutoff[e];

    float2 w0 = ((const float2*)(bf + 0 * NF))[t];
    float2 w1 = ((const float2*)(bf + 1 * NF))[t];
    float2 w2 = ((const float2*)(bf + 2 * NF))[t];
    #pragma unroll
    for (int r = 0; r < NRAD; ++r) {
        const float2* row = (const float2*)(Wf + r * (3 * NF));
        w0 = f2fma(rad[r], row[t],       w0);
        w1 = f2fma(rad[r], row[t + 64],  w1);
        w2 = f2fma(rad[r], row[t + 128], w2);
    }
    w0.x *= cut; w0.y *= cut;
    w1.x *= cut; w1.y *= cut;
    w2.x *= cut; w2.y *= cut;

    float2* wp = (float2*)(Wij + (size_t)e * (3 * NF));
    wp[t]       = w0;
    wp[t + 64]  = w1;
    wp[t + 128] = w2;

    __syncthreads();
    float* mp = Mall + (size_t)e * MSTRIDE;
    if (t < 81) mp[t] = Msh[t];
    if (t + 64 < 81) mp[t + 64] = Msh[t + 64];
}

// ---------------- kernel 2: 4 waves per atom ----------------
__global__ __launch_bounds__(256) void atom_kernel(
    const float* __restrict__ x,        // [A, 9, 128]
    const float* __restrict__ Mall,     // [E, MSTRIDE]
    const float* __restrict__ Wij,      // [E, 3, 128]
    const int* __restrict__ cnt,        // [A]
    const int* __restrict__ elist,      // [A, MAXDEG]
    const int* __restrict__ idx_j,      // [E]
    float* __restrict__ out)            // [A, 9, 128]
{
    const int a = blockIdx.x;
    const int tid = threadIdx.x;
    const int w = tid >> 6;             // wave 0..3
    const int t = tid & 63;             // f-pair: f = 2t, 2t+1
    const int deg = min(cnt[a], MAXDEG);
    const int* el = elist + a * MAXDEG;

    __shared__ float sacc[4][S9][NF];   // per-wave partials

    float2 acc[S9];
    #pragma unroll
    for (int s = 0; s < S9; ++s) acc[s] = make_float2(0.f, 0.f);

    // software-pipelined edge loop: wave w owns k = w, w+4, ...
    int k = w;
    int e_cur = 0, j_cur = 0;
    if (k < deg) {
        e_cur = __builtin_amdgcn_readfirstlane(el[k]);
        j_cur = __builtin_amdgcn_readfirstlane(idx_j[e_cur]);
    }
    while (k < deg) {
        const int kn = k + 4;
        int e_nx = 0, j_nx = 0;
        if (kn < deg) {
            e_nx = __builtin_amdgcn_readfirstlane(el[kn]);
            j_nx = __builtin_amdgcn_readfirstlane(idx_j[e_nx]);
        }

        const float*  Me = Mall + (size_t)e_cur * MSTRIDE;              // uniform -> s_load
        const float2* xp = (const float2*)(x + (size_t)j_cur * (S9 * NF)) + t;
        const float2* wp = (const float2*)(Wij + (size_t)e_cur * (3 * NF)) + t;

        float2 xj[S9];
        #pragma unroll
        for (int s = 0; s < S9; ++s) xj[s] = xp[s * 64];
        const float2 wl0 = wp[0];
        const float2 wl1 = wp[64];
        const float2 wl2 = wp[128];

        // ts[s3] = sum_s1 M[s1][s3] * xj[s1]   (M stored [s1][s3])
        float2 ts[S9];
        #pragma unroll
        for (int s3 = 0; s3 < S9; ++s3)
            ts[s3] = make_float2(Me[s3] * xj[0].x, Me[s3] * xj[0].y);
        #pragma unroll
        for (int s1 = 1; s1 < S9; ++s1) {
            #pragma unroll
            for (int s3 = 0; s3 < S9; ++s3)
                ts[s3] = f2fma(Me[s1 * S9 + s3], xj[s1], ts[s3]);
        }
        #pragma unroll
        for (int s3 = 0; s3 < S9; ++s3) {
            const float2 ww = (s3 == 0) ? wl0 : ((s3 < 4) ? wl1 : wl2);
            acc[s3].x = fmaf(ww.x, ts[s3].x, acc[s3].x);
            acc[s3].y = fmaf(ww.y, ts[s3].y, acc[s3].y);
        }

        k = kn; e_cur = e_nx; j_cur = j_nx;
    }

    // write wave partials to LDS
    #pragma unroll
    for (int s = 0; s < S9; ++s)
        *(float2*)&sacc[w][s][2 * t] = acc[s];
    __syncthreads();

    // 256 threads reduce 576 float2 outputs (4 partials each), coalesced store
    for (int idx = tid; idx < S9 * 64; idx += 256) {
        const int s  = idx >> 6;        // 0..8
        const int tp = idx & 63;        // f-pair
        float2 v0 = *(const float2*)&sacc[0][s][2 * tp];
        float2 v1 = *(const float2*)&sacc[1][s][2 * tp];
        float2 v2 = *(const float2*)&sacc[2][s][2 * tp];
        float2 v3 = *(const float2*)&sacc[3][s][2 * tp];
        float2 r = make_float2((v0.x + v1.x) + (v2.x + v3.x),
                               (v0.y + v1.y) + (v2.y + v3.y));
        *(float2*)&out[(size_t)a * (S9 * NF) + s * NF + 2 * tp] = r;
    }
}

extern "C" void kernel_launch(void* const* d_in, const int* in_sizes, int n_in,
                              void* d_out, int out_size, void* d_ws, size_t ws_size,
                              hipStream_t stream) {
    const float* x       = (const float*)d_in[0];
    const float* radial  = (const float*)d_in[1];
    const float* dir     = (const float*)d_in[2];
    const float* cutoff  = (const float*)d_in[3];
    const float* Wf      = (const float*)d_in[4];
    const float* bf      = (const float*)d_in[5];
    const float* cg_vals = (const float*)d_in[6];
    const int*   idx_i   = (const int*)d_in[7];
    const int*   idx_j   = (const int*)d_in[8];
    const int*   cg_i1   = (const int*)d_in[9];
    const int*   cg_i2   = (const int*)d_in[10];
    const int*   cg_i3   = (const int*)d_in[11];
    // d_in[12] = w_idx: unused (w_idx[k] == l(cg_idx_out[k]), folded into kernel)

    const int E   = in_sizes[7];
    const int ncg = in_sizes[6];
    const int A   = in_sizes[0] / (S9 * NF);

    // ws layout: cnt[A] | elist[A*MAXDEG] | (align 512B) | Mall[E*96] | Wij[E*384]
    int* cnt   = (int*)d_ws;
    int* elist = cnt + A;
    size_t off = ((size_t)(A + A * MAXDEG) * sizeof(int) + 511) & ~(size_t)511;
    float* Mall = (float*)((char*)d_ws + off);
    float* Wij  = Mall + (size_t)E * MSTRIDE;

    hipMemsetAsync(cnt, 0, (size_t)A * sizeof(int), stream);

    prep_kernel<<<E, 64, 0, stream>>>(
        radial, dir, cutoff, Wf, bf, cg_vals, idx_i,
        cg_i1, cg_i2, cg_i3, ncg, cnt, elist, Mall, Wij);

    atom_kernel<<<A, 256, 0, stream>>>(
        x, Mall, Wij, cnt, elist, idx_j, (float*)d_out);
}